// Round 1
// baseline (50.972 us; speedup 1.0000x reference)
//
#include <hip/hip_runtime.h>
#include <hip/hip_fp16.h>
#include <math.h>

#define L_TOTAL 49152
#define TILE 512
#define NTILES 96   // L_TOTAL / TILE

__device__ __forceinline__ float4 f4add(float4 a, float4 b) {
  return make_float4(a.x + b.x, a.y + b.y, a.z + b.z, a.w + b.w);
}

// Emulate np.float32 -> float16 (round-nearest-even, incl. subnormals) -> float32.
// Input x is positive and finite (x = 1/(l+1) <= 1).
__device__ __forceinline__ float fp16_roundtrip_pos(float x) {
  unsigned u = __float_as_uint(x);
  int e = (int)((u >> 23) & 0xffu) - 127;
  unsigned m = (u & 0x7fffffu) | 0x800000u;          // 24-bit mantissa
  int shift = (e >= -14) ? 13 : (13 + (-14 - e));    // extra shift for subnormals
  if (shift >= 25) return 0.0f;                      // underflow
  unsigned keep = m >> shift;
  unsigned rem = m & ((1u << shift) - 1u);
  unsigned halfbit = 1u << (shift - 1);
  if (rem > halfbit || (rem == halfbit && (keep & 1u))) keep++;
  return ldexpf((float)keep, e + shift - 23);
}

// Kernel 1: g[b,l,c] = sum_f relu(s[b,l]*W_in[f] + pos_enc[l,f]) * W_final[f,c]
// One wave per row l; each lane owns 16 f-values (4 float4 groups, stride-64
// coalesced). W_in/W_final fragments live in registers, reused for 16 rows.
__global__ __launch_bounds__(256, 4) void compute_g_kernel(
    const int* __restrict__ ex, const float4* __restrict__ win4,
    const float4* __restrict__ pos4, const float4* __restrict__ wf4,
    float4* __restrict__ g4) {
  const int lane = threadIdx.x & 63;
  const int wave = threadIdx.x >> 6;
  const int rowBase = blockIdx.x * 64 + wave * 16;

  float4 win[4];
  float4 wf[4][4];
#pragma unroll
  for (int j = 0; j < 4; ++j) {
    const int fi = j * 64 + lane;  // float4 index into the 1024-long f axis
    win[j] = win4[fi];
#pragma unroll
    for (int k = 0; k < 4; ++k) wf[j][k] = wf4[fi * 4 + k];  // W_final row f
  }

  for (int r = 0; r < 16; ++r) {
    const int l = rowBase + r;
    const float s0 = (float)ex[l] - 3.0f;            // ((e/4*2-1)*2-1) == e-3
    const float s1 = (float)ex[L_TOTAL + l] - 3.0f;
    float4 a0 = make_float4(0.f, 0.f, 0.f, 0.f);
    float4 a1 = make_float4(0.f, 0.f, 0.f, 0.f);
#pragma unroll
    for (int j = 0; j < 4; ++j) {
      const float4 p = pos4[(size_t)l * 256 + j * 64 + lane];
      const float pc[4] = {p.x, p.y, p.z, p.w};
      const float wc[4] = {win[j].x, win[j].y, win[j].z, win[j].w};
#pragma unroll
      for (int k = 0; k < 4; ++k) {
        const float t0 = fmaxf(fmaf(s0, wc[k], pc[k]), 0.0f);
        const float t1 = fmaxf(fmaf(s1, wc[k], pc[k]), 0.0f);
        const float4 w = wf[j][k];
        a0.x = fmaf(t0, w.x, a0.x); a0.y = fmaf(t0, w.y, a0.y);
        a0.z = fmaf(t0, w.z, a0.z); a0.w = fmaf(t0, w.w, a0.w);
        a1.x = fmaf(t1, w.x, a1.x); a1.y = fmaf(t1, w.y, a1.y);
        a1.z = fmaf(t1, w.z, a1.z); a1.w = fmaf(t1, w.w, a1.w);
      }
    }
#pragma unroll
    for (int off = 32; off > 0; off >>= 1) {
      a0.x += __shfl_xor(a0.x, off); a0.y += __shfl_xor(a0.y, off);
      a0.z += __shfl_xor(a0.z, off); a0.w += __shfl_xor(a0.w, off);
      a1.x += __shfl_xor(a1.x, off); a1.y += __shfl_xor(a1.y, off);
      a1.z += __shfl_xor(a1.z, off); a1.w += __shfl_xor(a1.w, off);
    }
    if (lane == 0) {
      g4[l] = a0;
      g4[L_TOTAL + l] = a1;
    }
  }
}

// Kernel 2: per-tile sums of g (tiles of 512 rows).
__global__ __launch_bounds__(256) void tile_sums_kernel(
    const float4* __restrict__ g4, float4* __restrict__ tsum) {
  const int t = blockIdx.x;
  const int b = blockIdx.y;
  const int tid = threadIdx.x;
  const float4* base = g4 + (size_t)b * L_TOTAL + (size_t)t * TILE;
  float4 v = f4add(base[tid], base[tid + 256]);
#pragma unroll
  for (int off = 32; off > 0; off >>= 1) {
    v.x += __shfl_xor(v.x, off); v.y += __shfl_xor(v.y, off);
    v.z += __shfl_xor(v.z, off); v.w += __shfl_xor(v.w, off);
  }
  __shared__ float4 ws[4];
  if ((tid & 63) == 0) ws[tid >> 6] = v;
  __syncthreads();
  if (tid == 0) {
    tsum[b * NTILES + t] = f4add(f4add(ws[0], ws[1]), f4add(ws[2], ws[3]));
  }
}

// Kernel 3: exclusive scan of the 96 tile sums per batch (single block).
__global__ __launch_bounds__(256) void scan_tiles_kernel(
    const float4* __restrict__ tsum, float4* __restrict__ toff) {
  __shared__ float4 buf[2][128];
  const int b = threadIdx.x >> 7;
  const int i = threadIdx.x & 127;
  float4 v = make_float4(0.f, 0.f, 0.f, 0.f);
  if (i < NTILES) v = tsum[b * NTILES + i];
  buf[b][i] = v;
  __syncthreads();
#pragma unroll
  for (int d = 1; d < 128; d <<= 1) {
    float4 t = make_float4(0.f, 0.f, 0.f, 0.f);
    if (i >= d) t = buf[b][i - d];
    __syncthreads();
    if (i >= d) buf[b][i] = f4add(buf[b][i], t);  // each thread updates own slot
    __syncthreads();
  }
  if (i < NTILES)
    toff[b * NTILES + i] = (i == 0) ? make_float4(0.f, 0.f, 0.f, 0.f)
                                    : buf[b][i - 1];
}

// Kernel 4: intra-tile inclusive scan + tile offset, then *factor + b_final.
__global__ __launch_bounds__(512) void scan_out_kernel(
    const float4* __restrict__ g4, const float4* __restrict__ toff,
    const float* __restrict__ b_final, float4* __restrict__ out4) {
  const int t = blockIdx.x;
  const int b = blockIdx.y;
  const int tid = threadIdx.x;
  const int lane = tid & 63;
  const int wv = tid >> 6;
  const int l = t * TILE + tid;
  float4 v = g4[(size_t)b * L_TOTAL + l];
#pragma unroll
  for (int d = 1; d < 64; d <<= 1) {
    const float ux = __shfl_up(v.x, d);
    const float uy = __shfl_up(v.y, d);
    const float uz = __shfl_up(v.z, d);
    const float uw = __shfl_up(v.w, d);
    if (lane >= d) { v.x += ux; v.y += uy; v.z += uz; v.w += uw; }
  }
  __shared__ float4 wsum[8];
  __shared__ float4 woff[8];
  if (lane == 63) wsum[wv] = v;
  __syncthreads();
  if (tid == 0) {
    float4 run = make_float4(0.f, 0.f, 0.f, 0.f);
#pragma unroll
    for (int w = 0; w < 8; ++w) { woff[w] = run; run = f4add(run, wsum[w]); }
  }
  __syncthreads();
  const float4 base = f4add(woff[wv], toff[b * NTILES + t]);
  v = f4add(v, base);
  const float factor = fp16_roundtrip_pos(1.0f / (float)(l + 1));
  const float4 bf = make_float4(b_final[0], b_final[1], b_final[2], b_final[3]);
  float4 o;
  o.x = fmaf(v.x, factor, bf.x);
  o.y = fmaf(v.y, factor, bf.y);
  o.z = fmaf(v.z, factor, bf.z);
  o.w = fmaf(v.w, factor, bf.w);
  out4[(size_t)b * L_TOTAL + l] = o;
}

extern "C" void kernel_launch(void* const* d_in, const int* in_sizes, int n_in,
                              void* d_out, int out_size, void* d_ws, size_t ws_size,
                              hipStream_t stream) {
  const int* ex = (const int*)d_in[0];            // example [2,128,128,3] int32
  const float4* win4 = (const float4*)d_in[1];    // W_in [1,1024]
  const float4* pos4 = (const float4*)d_in[2];    // pos_enc [49152,1024]
  const float4* wf4 = (const float4*)d_in[3];     // W_final [1024,4]
  const float* bfin = (const float*)d_in[4];      // b_final [4]

  float4* g4 = (float4*)d_ws;                                   // [2*49152] float4
  float4* tsum = (float4*)((char*)d_ws + (size_t)2 * L_TOTAL * sizeof(float4));
  float4* toff = tsum + 2 * NTILES;

  compute_g_kernel<<<L_TOTAL / 64, 256, 0, stream>>>(ex, win4, pos4, wf4, g4);
  tile_sums_kernel<<<dim3(NTILES, 2), 256, 0, stream>>>(g4, tsum);
  scan_tiles_kernel<<<1, 256, 0, stream>>>(tsum, toff);
  scan_out_kernel<<<dim3(NTILES, 2), 512, 0, stream>>>(g4, toff, bfin,
                                                       (float4*)d_out);
}

// Round 4
// 48.012 us; speedup vs baseline: 1.0617x; 1.0617x over previous
//
#include <hip/hip_runtime.h>
#include <math.h>

#define L_TOTAL 49152
#define NBLK 512
#define ROWS_PER_BLK 96   // L_TOTAL / NBLK
#define ROWS_PER_WAVE 24  // 4 waves per block

__device__ __forceinline__ float4 f4add(float4 a, float4 b) {
  return make_float4(a.x + b.x, a.y + b.y, a.z + b.z, a.w + b.w);
}

// Emulate np.float32 -> float16 (RNE, incl. subnormals) -> float32.
// Input x is positive and finite (x = 1/(l+1) <= 1).
__device__ __forceinline__ float fp16_roundtrip_pos(float x) {
  unsigned u = __float_as_uint(x);
  int e = (int)((u >> 23) & 0xffu) - 127;
  unsigned m = (u & 0x7fffffu) | 0x800000u;          // 24-bit mantissa
  int shift = (e >= -14) ? 13 : (13 + (-14 - e));    // extra shift for subnormals
  if (shift >= 25) return 0.0f;                      // underflow
  unsigned keep = m >> shift;
  unsigned rem = m & ((1u << shift) - 1u);
  unsigned halfbit = 1u << (shift - 1);
  if (rem > halfbit || (rem == halfbit && (keep & 1u))) keep++;
  return ldexpf((float)keep, e + shift - 23);
}

// Kernel A: g[b,l,c] = sum_f relu(s[b,l]*W_in[f]+pos_enc[l,f])*W_final[f,c]
// 96 rows per block (24 per wave). Rows staged in LDS, dumped coalesced to
// global g, plus per-block partial sums pp. Cross-block visibility comes from
// the kernel boundary (the cooperative grid.sync path proved broken here).
__global__ __launch_bounds__(256, 2) void gpart_kernel(
    const int* __restrict__ ex, const float4* __restrict__ win4,
    const float4* __restrict__ pos4, const float4* __restrict__ wf4,
    float4* __restrict__ g4, float4* __restrict__ pp) {
  __shared__ float4 sg[2][ROWS_PER_BLK];
  __shared__ float4 wpart[2][4];

  const int lane = threadIdx.x & 63;
  const int wv = threadIdx.x >> 6;
  const int rowBase = blockIdx.x * ROWS_PER_BLK + wv * ROWS_PER_WAVE;

  // W_in / W_final fragments in registers, reused for all 24 rows.
  float4 win[4];
  float4 wf[4][4];
#pragma unroll
  for (int j = 0; j < 4; ++j) {
    const int fi = j * 64 + lane;  // float4 index into the 1024-long f axis
    win[j] = win4[fi];
#pragma unroll
    for (int k = 0; k < 4; ++k) wf[j][k] = wf4[fi * 4 + k];
  }

  float4 bp0 = make_float4(0.f, 0.f, 0.f, 0.f);
  float4 bp1 = make_float4(0.f, 0.f, 0.f, 0.f);

  for (int r = 0; r < ROWS_PER_WAVE; ++r) {
    const int l = rowBase + r;
    const float s0 = (float)ex[l] - 3.0f;            // ((e/4*2-1)*2-1) == e-3
    const float s1 = (float)ex[L_TOTAL + l] - 3.0f;
    float4 a0 = make_float4(0.f, 0.f, 0.f, 0.f);
    float4 a1 = make_float4(0.f, 0.f, 0.f, 0.f);
#pragma unroll
    for (int j = 0; j < 4; ++j) {
      const float4 p = pos4[(size_t)l * 256 + j * 64 + lane];
      const float pc[4] = {p.x, p.y, p.z, p.w};
      const float wc[4] = {win[j].x, win[j].y, win[j].z, win[j].w};
#pragma unroll
      for (int k = 0; k < 4; ++k) {
        const float t0 = fmaxf(fmaf(s0, wc[k], pc[k]), 0.0f);
        const float t1 = fmaxf(fmaf(s1, wc[k], pc[k]), 0.0f);
        const float4 w = wf[j][k];
        a0.x = fmaf(t0, w.x, a0.x); a0.y = fmaf(t0, w.y, a0.y);
        a0.z = fmaf(t0, w.z, a0.z); a0.w = fmaf(t0, w.w, a0.w);
        a1.x = fmaf(t1, w.x, a1.x); a1.y = fmaf(t1, w.y, a1.y);
        a1.z = fmaf(t1, w.z, a1.z); a1.w = fmaf(t1, w.w, a1.w);
      }
    }
#pragma unroll
    for (int off = 32; off > 0; off >>= 1) {
      a0.x += __shfl_xor(a0.x, off); a0.y += __shfl_xor(a0.y, off);
      a0.z += __shfl_xor(a0.z, off); a0.w += __shfl_xor(a0.w, off);
      a1.x += __shfl_xor(a1.x, off); a1.y += __shfl_xor(a1.y, off);
      a1.z += __shfl_xor(a1.z, off); a1.w += __shfl_xor(a1.w, off);
    }
    bp0 = f4add(bp0, a0);
    bp1 = f4add(bp1, a1);
    if (lane == 0) {
      sg[0][wv * ROWS_PER_WAVE + r] = a0;
      sg[1][wv * ROWS_PER_WAVE + r] = a1;
    }
  }

  if (lane == 0) { wpart[0][wv] = bp0; wpart[1][wv] = bp1; }
  __syncthreads();

  // Coalesced dump of the 192 g rows + 2 partial sums.
  if (threadIdx.x < 2 * ROWS_PER_BLK) {
    const int bb = threadIdx.x / ROWS_PER_BLK;
    const int i = threadIdx.x - bb * ROWS_PER_BLK;
    g4[(size_t)bb * L_TOTAL + blockIdx.x * ROWS_PER_BLK + i] = sg[bb][i];
  }
  if (threadIdx.x < 2) {
    const int bb = threadIdx.x;
    pp[bb * NBLK + blockIdx.x] =
        f4add(f4add(wpart[bb][0], wpart[bb][1]),
              f4add(wpart[bb][2], wpart[bb][3]));
  }
}

// Kernel B: per block -- offset = sum of preceding blocks' partials (L2-hot),
// intra-block inclusive scan of 96 rows per batch, *fp16(1/(l+1)), +b_final.
__global__ __launch_bounds__(256, 2) void scan_kernel(
    const float4* __restrict__ g4, const float4* __restrict__ pp,
    const float* __restrict__ bfin, float4* __restrict__ out4) {
  __shared__ float4 sg[2][ROWS_PER_BLK];
  __shared__ float4 wq[2][4];
  __shared__ float4 boffs[2];

  const int tid = threadIdx.x;
  const int lane = tid & 63;
  const int wv = tid >> 6;
  const int bid = blockIdx.x;

  // Load this block's 192 g rows into LDS.
  if (tid < 2 * ROWS_PER_BLK) {
    const int bb = tid / ROWS_PER_BLK;
    const int i = tid - bb * ROWS_PER_BLK;
    sg[bb][i] = g4[(size_t)bb * L_TOTAL + bid * ROWS_PER_BLK + i];
  }

  // Offset: sum pp[j] for j < bid (both batches).
  float4 q0 = make_float4(0.f, 0.f, 0.f, 0.f);
  float4 q1 = make_float4(0.f, 0.f, 0.f, 0.f);
  for (int jj = tid; jj < bid; jj += 256) {
    q0 = f4add(q0, pp[jj]);
    q1 = f4add(q1, pp[NBLK + jj]);
  }
#pragma unroll
  for (int off = 32; off > 0; off >>= 1) {
    q0.x += __shfl_xor(q0.x, off); q0.y += __shfl_xor(q0.y, off);
    q0.z += __shfl_xor(q0.z, off); q0.w += __shfl_xor(q0.w, off);
    q1.x += __shfl_xor(q1.x, off); q1.y += __shfl_xor(q1.y, off);
    q1.z += __shfl_xor(q1.z, off); q1.w += __shfl_xor(q1.w, off);
  }
  if (lane == 0) { wq[0][wv] = q0; wq[1][wv] = q1; }
  __syncthreads();
  if (tid == 0) {
    boffs[0] = f4add(f4add(wq[0][0], wq[0][1]), f4add(wq[0][2], wq[0][3]));
    boffs[1] = f4add(f4add(wq[1][0], wq[1][1]), f4add(wq[1][2], wq[1][3]));
  }
  __syncthreads();

  // Hillis-Steele inclusive scan over the 96 rows per batch.
  const bool act = tid < 2 * ROWS_PER_BLK;
  const int bb = tid / ROWS_PER_BLK;       // 0 or 1 when act
  const int i = tid - bb * ROWS_PER_BLK;
#pragma unroll
  for (int d = 1; d < ROWS_PER_BLK; d <<= 1) {
    float4 addv = make_float4(0.f, 0.f, 0.f, 0.f);
    if (act && i >= d) addv = sg[bb][i - d];
    __syncthreads();
    if (act && i >= d) sg[bb][i] = f4add(sg[bb][i], addv);
    __syncthreads();
  }
  if (act) {
    const int l = bid * ROWS_PER_BLK + i;
    const float4 v = f4add(sg[bb][i], boffs[bb]);
    const float factor = fp16_roundtrip_pos(1.0f / (float)(l + 1));
    float4 o;
    o.x = fmaf(v.x, factor, bfin[0]);
    o.y = fmaf(v.y, factor, bfin[1]);
    o.z = fmaf(v.z, factor, bfin[2]);
    o.w = fmaf(v.w, factor, bfin[3]);
    out4[(size_t)bb * L_TOTAL + l] = o;
  }
}

extern "C" void kernel_launch(void* const* d_in, const int* in_sizes, int n_in,
                              void* d_out, int out_size, void* d_ws, size_t ws_size,
                              hipStream_t stream) {
  const int* ex = (const int*)d_in[0];            // example [2,128,128,3] int32
  const float4* win4 = (const float4*)d_in[1];    // W_in [1,1024]
  const float4* pos4 = (const float4*)d_in[2];    // pos_enc [49152,1024]
  const float4* wf4 = (const float4*)d_in[3];     // W_final [1024,4]
  const float* bfin = (const float*)d_in[4];      // b_final [4]
  float4* out4 = (float4*)d_out;

  float4* g4 = (float4*)d_ws;                     // [2*L_TOTAL] float4
  float4* pp = g4 + (size_t)2 * L_TOTAL;          // [2*NBLK] float4

  gpart_kernel<<<NBLK, 256, 0, stream>>>(ex, win4, pos4, wf4, g4, pp);
  scan_kernel<<<NBLK, 256, 0, stream>>>(g4, pp, bfin, out4);
}